// Round 2
// baseline (583.535 us; speedup 1.0000x reference)
//
#include <hip/hip_runtime.h>
#include <cstdint>
#include <cstddef>

#define NN 8192
#define FIN 256
#define FOUT 128
#define SLOPE 0.2f
#define SHIFT 8.0f

typedef float f32x4 __attribute__((ext_vector_type(4)));
typedef __bf16 bf16x8 __attribute__((ext_vector_type(8)));
typedef int i32x4 __attribute__((ext_vector_type(4)));
typedef unsigned int u32x4 __attribute__((ext_vector_type(4)));
typedef unsigned int u32x2 __attribute__((ext_vector_type(2)));

__device__ __forceinline__ unsigned short f2bf(float f) {
  return __builtin_bit_cast(unsigned short, (__bf16)f);
}

// ---------------------------------------------------------------------------
// Kernel A: h = x @ W (fp32 accumulate), stored TRANSPOSED as bf16 ht[FOUT][NN]
// ---------------------------------------------------------------------------
__global__ __launch_bounds__(256) void k_hw(const float* __restrict__ x,
                                            const float* __restrict__ W,
                                            unsigned short* __restrict__ ht) {
  __shared__ float xs[32 * 260];
  const int tid = threadIdx.x;
  const int rowbase = blockIdx.x * 32;

  #pragma unroll
  for (int it = 0; it < 8; ++it) {
    int idx = it * 1024 + tid * 4;
    int row = idx >> 8, k = idx & 255;
    f32x4 v = *(const f32x4*)(x + (size_t)(rowbase + row) * FIN + k);
    *(f32x4*)(&xs[row * 260 + k]) = v;
  }
  __syncthreads();

  const int tx = tid & 31;   // cols tx*4 .. tx*4+3
  const int ty = tid >> 5;   // rows ty*4 .. ty*4+3
  float acc[4][4];
  #pragma unroll
  for (int r = 0; r < 4; ++r)
    #pragma unroll
    for (int c = 0; c < 4; ++c) acc[r][c] = 0.f;

  #pragma unroll 4
  for (int k = 0; k < FIN; ++k) {
    f32x4 wv = *(const f32x4*)(W + k * FOUT + tx * 4);
    #pragma unroll
    for (int r = 0; r < 4; ++r) {
      float xv = xs[(ty * 4 + r) * 260 + k];
      acc[r][0] += xv * wv[0];
      acc[r][1] += xv * wv[1];
      acc[r][2] += xv * wv[2];
      acc[r][3] += xv * wv[3];
    }
  }

  #pragma unroll
  for (int c = 0; c < 4; ++c) {
    int col = tx * 4 + c;
    unsigned int lo = (unsigned int)f2bf(acc[0][c]) | ((unsigned int)f2bf(acc[1][c]) << 16);
    unsigned int hi = (unsigned int)f2bf(acc[2][c]) | ((unsigned int)f2bf(acc[3][c]) << 16);
    u32x2 p; p[0] = lo; p[1] = hi;
    *(u32x2*)(ht + (size_t)col * NN + rowbase + ty * 4) = p;
  }
}

// ---------------------------------------------------------------------------
// Kernel B: s_src[i] = h[i,:]·a1, s_dst[i] = h[i,:]·a2 from transposed bf16 ht.
// ---------------------------------------------------------------------------
__global__ __launch_bounds__(256) void k_s(const unsigned short* __restrict__ ht,
                                           const float* __restrict__ a1,
                                           const float* __restrict__ a2,
                                           float* __restrict__ s_src,
                                           float* __restrict__ s_dst) {
  const int i = blockIdx.x * 256 + threadIdx.x;
  float s1 = 0.f, s2 = 0.f;
  #pragma unroll 8
  for (int f = 0; f < FOUT; ++f) {
    float hv = (float)__builtin_bit_cast(__bf16, ht[(size_t)f * NN + i]);
    s1 += hv * a1[f];
    s2 += hv * a2[f];
  }
  s_src[i] = s1;
  s_dst[i] = s2;
}

// ---------------------------------------------------------------------------
// Kernel C: fused mask -> shifted exp -> (attention @ h) / rowsum + bias.
// LAYOUT-PROOF version:
//  * denominator comes from a 9th MFMA with B = all-ones, so num/den share the
//    exact same data path slot-by-slot (immune to wrong A/B/C/D layout maps).
//  * C/D slot -> (logical row, logical col) is measured at runtime by two
//    probe MFMAs (A = row label, B = 1/32 splat and vice versa); all probe
//    values are exact in bf16/fp32 (m*2^-5, partial sums <= 480 < 2^24).
// ---------------------------------------------------------------------------
__global__ __launch_bounds__(256) void k_gat(const int* __restrict__ adj,
                                             const unsigned short* __restrict__ ht,
                                             const float* __restrict__ s_src,
                                             const float* __restrict__ s_dst,
                                             const float* __restrict__ bias,
                                             float* __restrict__ out) {
  __shared__ float accs[4][16][128];
  __shared__ float dpart[4][16];
  __shared__ float lsum[16];

  const int tid = threadIdx.x;
  const int wave = tid >> 6;
  const int lane = tid & 63;
  const int quad = lane >> 4;
  const int m = lane & 15;          // my A-row / B-col placement label
  const int rowbase = blockIdx.x * 16;
  const int JPW = NN / 4;
  const int j0 = wave * JPW;

  // ---- runtime layout probes ----
  bf16x8 pm, pinv, pones;
  #pragma unroll
  for (int jj = 0; jj < 8; ++jj) {
    pm[jj]    = (__bf16)(float)m;
    pinv[jj]  = (__bf16)0.03125f;   // 1/32, exact
    pones[jj] = (__bf16)1.0f;
  }
  f32x4 z = {0.f, 0.f, 0.f, 0.f};
  f32x4 rp = __builtin_amdgcn_mfma_f32_16x16x32_bf16(pm, pinv, z, 0, 0, 0);
  f32x4 cp = __builtin_amdgcn_mfma_f32_16x16x32_bf16(pinv, pm, z, 0, 0, 0);
  int rowmap[4], colmap[4];
  #pragma unroll
  for (int r = 0; r < 4; ++r) {
    rowmap[r] = ((int)(rp[r] + 0.5f)) & 15;
    colmap[r] = ((int)(cp[r] + 0.5f)) & 15;
  }

  const float si = s_src[rowbase + m];
  const float c0 = si + SHIFT;
  const float ci = fmaxf(c0, SLOPE * c0);  // leakyrelu(si + SHIFT) >= row max

  const unsigned short* hp[8];
  #pragma unroll
  for (int t = 0; t < 8; ++t)
    hp[t] = ht + (size_t)(t * 16 + m) * NN + quad * 8;

  const int* ap = adj + (size_t)(rowbase + m) * NN + quad * 8;

  f32x4 acc[8];
  #pragma unroll
  for (int t = 0; t < 8; ++t) acc[t] = z;
  f32x4 den = z;

  for (int jb = j0; jb < j0 + JPW; jb += 32) {
    i32x4 A0 = __builtin_nontemporal_load((const i32x4*)(ap + jb));
    i32x4 A1 = __builtin_nontemporal_load((const i32x4*)(ap + jb + 4));
    f32x4 t0 = *(const f32x4*)(s_dst + jb + quad * 8);
    f32x4 t1 = *(const f32x4*)(s_dst + jb + quad * 8 + 4);

    bf16x8 af;
    #pragma unroll
    for (int jj = 0; jj < 8; ++jj) {
      float tv = (jj < 4) ? t0[jj] : t1[jj - 4];
      int av = (jj < 4) ? A0[jj] : A1[jj - 4];
      float xv = si + tv;
      float e = fmaxf(xv, SLOPE * xv);          // leakyrelu
      float wf = (av != 0) ? __expf(e - ci) : 0.f;
      af[jj] = (__bf16)wf;
    }

    #pragma unroll
    for (int t = 0; t < 8; ++t) {
      bf16x8 bfr = __builtin_bit_cast(bf16x8, *(const u32x4*)(hp[t] + jb));
      acc[t] = __builtin_amdgcn_mfma_f32_16x16x32_bf16(af, bfr, acc[t], 0, 0, 0);
    }
    den = __builtin_amdgcn_mfma_f32_16x16x32_bf16(af, pones, den, 0, 0, 0);
  }

  // ---- epilogue: cross-wave combine (indices from probes) ----
  #pragma unroll
  for (int t = 0; t < 8; ++t)
    #pragma unroll
    for (int r = 0; r < 4; ++r)
      accs[wave][rowmap[r]][t * 16 + colmap[r]] = acc[t][r];
  if (m == 0) {
    #pragma unroll
    for (int r = 0; r < 4; ++r)
      dpart[wave][rowmap[r]] = den[r];
  }
  __syncthreads();

  if (tid < 16) {
    float l = 0.f;
    #pragma unroll
    for (int w2 = 0; w2 < 4; ++w2) l += dpart[w2][tid];
    lsum[tid] = l;
  }
  __syncthreads();

  #pragma unroll
  for (int p = 0; p < 8; ++p) {
    int idx = p * 256 + tid;
    int row = idx >> 7, col = idx & 127;
    float v = accs[0][row][col] + accs[1][row][col] +
              accs[2][row][col] + accs[3][row][col];
    out[(size_t)(rowbase + row) * FOUT + col] = v / lsum[row] + bias[col];
  }
}

// ---------------------------------------------------------------------------
extern "C" void kernel_launch(void* const* d_in, const int* in_sizes, int n_in,
                              void* d_out, int out_size, void* d_ws, size_t ws_size,
                              hipStream_t stream) {
  const float* x    = (const float*)d_in[0];
  const int*   adj  = (const int*)d_in[1];
  const float* W    = (const float*)d_in[2];
  const float* a1   = (const float*)d_in[3];
  const float* a2   = (const float*)d_in[4];
  const float* bias = (const float*)d_in[5];
  float* out = (float*)d_out;

  char* ws = (char*)d_ws;
  unsigned short* ht = (unsigned short*)ws;                    // 2 MB
  float* s_src = (float*)(ws + (size_t)FOUT * NN * 2);         // 32 KB
  float* s_dst = s_src + NN;                                   // 32 KB

  k_hw<<<NN / 32, 256, 0, stream>>>(x, W, ht);
  k_s <<<NN / 256, 256, 0, stream>>>(ht, a1, a2, s_src, s_dst);
  k_gat<<<NN / 16, 256, 0, stream>>>(adj, ht, s_src, s_dst, bias, out);
}

// Round 3
// 552.947 us; speedup vs baseline: 1.0553x; 1.0553x over previous
//
#include <hip/hip_runtime.h>
#include <cstdint>
#include <cstddef>

#define NN 8192
#define FIN 256
#define FOUT 128
#define SLOPE 0.2f
#define SHIFT 8.0f
#define LOG2E 1.44269504f

typedef float f32x4 __attribute__((ext_vector_type(4)));
typedef __bf16 bf16x8 __attribute__((ext_vector_type(8)));
typedef int i32x4 __attribute__((ext_vector_type(4)));
typedef unsigned int u32x4 __attribute__((ext_vector_type(4)));

__device__ __forceinline__ unsigned short f2bf(float f) {
  return __builtin_bit_cast(unsigned short, (__bf16)f);
}

// async global->LDS, 16 B per lane; LDS dest = wave-uniform base + lane*16
__device__ __forceinline__ void async_cp16(void* lds, const void* g) {
  __builtin_amdgcn_global_load_lds(
      (const __attribute__((address_space(1))) void*)g,
      (__attribute__((address_space(3))) void*)lds, 16, 0, 0);
}

// ---------------------------------------------------------------------------
// Kernel A: h = x @ W (fp32 acc) -> ht[FOUT][NN] bf16 transposed, PLUS fused
// s_src = h@a1, s_dst = h@a2 (wave shuffle-reduce over the 32 col-lanes).
// 1024 blocks x 256 thr (8 rows/block) -> 4 blocks/CU, latency hidden.
// ---------------------------------------------------------------------------
__global__ __launch_bounds__(256, 4) void k_hw(const float* __restrict__ x,
                                               const float* __restrict__ W,
                                               const float* __restrict__ a1,
                                               const float* __restrict__ a2,
                                               unsigned short* __restrict__ ht,
                                               float* __restrict__ s_src,
                                               float* __restrict__ s_dst) {
  __shared__ float xs[8][256];
  const int tid = threadIdx.x;
  const int rowbase = blockIdx.x * 8;

  #pragma unroll
  for (int it = 0; it < 2; ++it) {
    int fi = it * 1024 + tid * 4;
    int r = fi >> 8, k = fi & 255;
    *(f32x4*)&xs[r][k] = *(const f32x4*)(x + (size_t)(rowbase + r) * FIN + k);
  }
  __syncthreads();

  const int r = tid >> 5;    // 0..7: row within block
  const int cg = tid & 31;   // col group: cols cg*4..cg*4+3
  f32x4 acc = {0.f, 0.f, 0.f, 0.f};

  #pragma unroll 4
  for (int k = 0; k < FIN; ++k) {
    f32x4 wv = *(const f32x4*)(W + k * FOUT + cg * 4);
    float xv = xs[r][k];     // broadcast (same addr across cg lanes)
    acc[0] += xv * wv[0];
    acc[1] += xv * wv[1];
    acc[2] += xv * wv[2];
    acc[3] += xv * wv[3];
  }

  const int row = rowbase + r;
  #pragma unroll
  for (int c = 0; c < 4; ++c)
    ht[(size_t)(cg * 4 + c) * NN + row] = f2bf(acc[c]);

  // fused s-vectors from fp32 accumulators
  f32x4 av1 = *(const f32x4*)(a1 + cg * 4);
  f32x4 av2 = *(const f32x4*)(a2 + cg * 4);
  float s1 = acc[0] * av1[0] + acc[1] * av1[1] + acc[2] * av1[2] + acc[3] * av1[3];
  float s2 = acc[0] * av2[0] + acc[1] * av2[1] + acc[2] * av2[2] + acc[3] * av2[3];
  #pragma unroll
  for (int off = 16; off > 0; off >>= 1) {   // xor<32 stays within the r-half
    s1 += __shfl_xor(s1, off, 64);
    s2 += __shfl_xor(s2, off, 64);
  }
  if (cg == 0) {
    s_src[row] = s1;
    s_dst[row] = s2;
  }
}

// ---------------------------------------------------------------------------
// Kernel B: fused mask -> shifted exp -> (attention @ h) / rowsum + bias.
//  * 512 blocks x 4 waves; block owns 16 rows; WAVES SPLIT THE F-TILES
//    (wave w -> output cols [w*32, w*32+32)), so the adj chunk is staged once
//    per block and shared by all waves.
//  * adj staged via global_load_lds (1 KB/instr, fully coalesced), double-
//    buffered, prefetch issued before compute -> deep vmem pipelining.
//  * denominator via ones-MFMA (layout-proof), per-wave redundant; C/D slot
//    mapping measured by runtime probe MFMAs (as round 2, which passed).
// ---------------------------------------------------------------------------
__global__ __launch_bounds__(256, 2) void k_gat(const int* __restrict__ adj,
                                                const unsigned short* __restrict__ ht,
                                                const float* __restrict__ s_src,
                                                const float* __restrict__ s_dst,
                                                const float* __restrict__ bias,
                                                float* __restrict__ out) {
  __shared__ int abuf[2][16][260];   // 260-int row stride: 16B-aligned + bank-spread

  const int tid = threadIdx.x;
  const int wave = tid >> 6;
  const int lane = tid & 63;
  const int quad = lane >> 4;
  const int m = lane & 15;
  const int rowbase = blockIdx.x * 16;

  // ---- runtime layout probes (exact in bf16/fp32) ----
  bf16x8 pm, pinv, pones;
  #pragma unroll
  for (int jj = 0; jj < 8; ++jj) {
    pm[jj] = (__bf16)(float)m;
    pinv[jj] = (__bf16)0.03125f;
    pones[jj] = (__bf16)1.0f;
  }
  f32x4 z = {0.f, 0.f, 0.f, 0.f};
  f32x4 rp = __builtin_amdgcn_mfma_f32_16x16x32_bf16(pm, pinv, z, 0, 0, 0);
  f32x4 cp = __builtin_amdgcn_mfma_f32_16x16x32_bf16(pinv, pm, z, 0, 0, 0);
  int rowmap[4], colmap[4];
  #pragma unroll
  for (int r = 0; r < 4; ++r) {
    rowmap[r] = ((int)(rp[r] + 0.5f)) & 15;
    colmap[r] = ((int)(cp[r] + 0.5f)) & 15;
  }

  const float si = s_src[rowbase + m];
  const float c0 = si + SHIFT;
  const float ci = fmaxf(c0, SLOPE * c0);   // leakyrelu(si+SHIFT) >= row max
  const float cl = ci * LOG2E;

  const int t0 = wave * 2, t1 = wave * 2 + 1;
  const unsigned short* hb0 = ht + (size_t)(t0 * 16 + m) * NN + quad * 8;
  const unsigned short* hb1 = ht + (size_t)(t1 * 16 + m) * NN + quad * 8;

  f32x4 acc0 = z, acc1 = z, den = z;

  // stage rows wave*4..wave*4+3 of a 256-j chunk into buffer b
  auto stage = [&](int c, int b) {
    #pragma unroll
    for (int rr = 0; rr < 4; ++rr) {
      int rowi = wave * 4 + rr;
      const unsigned int* g =
          (const unsigned int*)(adj + (size_t)(rowbase + rowi) * NN + c * 256) + lane * 4;
      async_cp16(&abuf[b][rowi][0], g);
    }
  };

  stage(0, 0);
  __syncthreads();   // chunk 0 staged (barrier forces vmcnt drain)

  for (int c = 0; c < 32; ++c) {
    const int b = c & 1;
    if (c + 1 < 32) stage(c + 1, b ^ 1);   // prefetch before compute

    const int* arow = &abuf[b][m][0];
    const int cbase = c * 256;

    #pragma unroll 4
    for (int s = 0; s < 8; ++s) {
      const int off = s * 32 + quad * 8;
      i32x4 A0 = *(const i32x4*)(arow + off);
      i32x4 A1 = *(const i32x4*)(arow + off + 4);
      f32x4 d0 = *(const f32x4*)(s_dst + cbase + off);
      f32x4 d1 = *(const f32x4*)(s_dst + cbase + off + 4);

      bf16x8 af;
      #pragma unroll
      for (int jj = 0; jj < 8; ++jj) {
        float tv = (jj < 4) ? d0[jj] : d1[jj - 4];
        int av = (jj < 4) ? A0[jj] : A1[jj - 4];
        float xv = si + tv;
        float e = fmaxf(xv, SLOPE * xv);                 // leakyrelu
        float wf = exp2f(fmaf(e, LOG2E, -cl));           // exp(e - ci)
        af[jj] = (av != 0) ? (__bf16)wf : (__bf16)0.0f;
      }

      bf16x8 b0 = __builtin_bit_cast(bf16x8, *(const u32x4*)(hb0 + cbase + s * 32));
      bf16x8 b1 = __builtin_bit_cast(bf16x8, *(const u32x4*)(hb1 + cbase + s * 32));
      acc0 = __builtin_amdgcn_mfma_f32_16x16x32_bf16(af, b0, acc0, 0, 0, 0);
      acc1 = __builtin_amdgcn_mfma_f32_16x16x32_bf16(af, b1, acc1, 0, 0, 0);
      den  = __builtin_amdgcn_mfma_f32_16x16x32_bf16(af, pones, den, 0, 0, 0);
    }
    __syncthreads();   // everyone done with buf b; prefetch (c+1) drained
  }

  // ---- epilogue: each wave owns disjoint cols; no cross-wave combine ----
  #pragma unroll
  for (int r = 0; r < 4; ++r) {
    float inv = 1.0f / den[r];
    int row = rowbase + rowmap[r];
    int ca = t0 * 16 + colmap[r];
    int cb = t1 * 16 + colmap[r];
    out[(size_t)row * FOUT + ca] = acc0[r] * inv + bias[ca];
    out[(size_t)row * FOUT + cb] = acc1[r] * inv + bias[cb];
  }
}

// ---------------------------------------------------------------------------
extern "C" void kernel_launch(void* const* d_in, const int* in_sizes, int n_in,
                              void* d_out, int out_size, void* d_ws, size_t ws_size,
                              hipStream_t stream) {
  const float* x    = (const float*)d_in[0];
  const int*   adj  = (const int*)d_in[1];
  const float* W    = (const float*)d_in[2];
  const float* a1   = (const float*)d_in[3];
  const float* a2   = (const float*)d_in[4];
  const float* bias = (const float*)d_in[5];
  float* out = (float*)d_out;

  char* ws = (char*)d_ws;
  unsigned short* ht = (unsigned short*)ws;                    // 2 MB
  float* s_src = (float*)(ws + (size_t)FOUT * NN * 2);         // 32 KB
  float* s_dst = s_src + NN;                                   // 32 KB

  k_hw<<<NN / 8, 256, 0, stream>>>(x, W, a1, a2, ht, s_src, s_dst);
  k_gat<<<NN / 16, 256, 0, stream>>>(adj, ht, s_src, s_dst, bias, out);
}